// Round 4
// baseline (294.756 us; speedup 1.0000x reference)
//
#include <hip/hip_runtime.h>
#include <hip/hip_bf16.h>
#include <cstdint>
#include <cstddef>

typedef unsigned short u16;
typedef __bf16 bf16x8 __attribute__((ext_vector_type(8)));
typedef float f32x4 __attribute__((ext_vector_type(4)));
typedef u16 u16x8 __attribute__((ext_vector_type(8)));

#define NROWS 15360   // B*C = 512*30
#define KDIM 512
#define BDIM 512
#define CDIM 30
#define TDIM 3
#define EDIM 6

typedef __attribute__((address_space(1))) const unsigned int gu32;
typedef __attribute__((address_space(3))) unsigned int lu32;

__device__ __forceinline__ void gload16(const u16* g, u16* l) {
  __builtin_amdgcn_global_load_lds((gu32*)g, (lu32*)l, 16, 0, 0);
}

__device__ __forceinline__ float bf2f(u16 u) {
  union { unsigned i; float f; } v; v.i = ((unsigned)u) << 16; return v.f;
}
__device__ __forceinline__ u16 f2bf(float f) {
  union { float f; unsigned i; } v; v.f = f;
  unsigned r = v.i + 0x7fffu + ((v.i >> 16) & 1u);
  return (u16)(r >> 16);
}

// ---------------- convert fp32 -> bf16 (vectorized) ----------------
__global__ __launch_bounds__(256) void cvt_bf16_kernel(const float* __restrict__ x,
                                                       u16* __restrict__ o, int n) {
  int i = (blockIdx.x * 256 + threadIdx.x) * 8;
  if (i + 8 > n) return;
  float4 a = *(const float4*)(x + i);
  float4 b = *(const float4*)(x + i + 4);
  u16x8 v;
  v[0] = f2bf(a.x); v[1] = f2bf(a.y); v[2] = f2bf(a.z); v[3] = f2bf(a.w);
  v[4] = f2bf(b.x); v[5] = f2bf(b.y); v[6] = f2bf(b.z); v[7] = f2bf(b.w);
  *(u16x8*)(o + i) = v;
}

// ---------------- transpose 512x512 fp32 -> bf16 [N][K] ----------------
__global__ __launch_bounds__(256) void transpose_w_kernel(
    const float* __restrict__ fc1, const float* __restrict__ fc2,
    const float* __restrict__ ew1, const float* __restrict__ ew2,
    const float* __restrict__ tw1, u16* __restrict__ wt) {
  int mid = blockIdx.y;
  const float* src;
  if (mid == 0) src = fc1;
  else if (mid == 1) src = fc2;
  else if (mid < 8) src = ew1 + (size_t)(mid - 2) * 262144;
  else if (mid < 14) src = ew2 + (size_t)(mid - 8) * 262144;
  else src = tw1 + (size_t)(mid - 14) * 262144;
  u16* dst = wt + (size_t)mid * 262144;

  int tile = blockIdx.x;
  int tr = (tile >> 3) * 64, tc = (tile & 7) * 64;
  __shared__ float t[64][65];
  int c = threadIdx.x & 63, r0 = threadIdx.x >> 6;
#pragma unroll
  for (int i = 0; i < 16; i++) {
    int r = r0 + i * 4;
    t[r][c] = src[(size_t)(tr + r) * 512 + tc + c];
  }
  __syncthreads();
#pragma unroll
  for (int i = 0; i < 16; i++) {
    int r = r0 + i * 4;
    dst[(size_t)(tc + r) * 512 + tr + c] = f2bf(t[c][r]);
  }
}

// ---------------- gate weight prep: WgT bf16 [32][512], cols 18..31 zero ----
__global__ __launch_bounds__(256) void gate_w_prep(const float* __restrict__ wg,
                                                   u16* __restrict__ WgT) {
  int col = blockIdx.x;  // 0..31
  for (int k = threadIdx.x; k < 512; k += 256) {
    u16 v = 0;
    if (col < 18) {
      int t = col / 6, e = col % 6;
      v = f2bf(wg[(size_t)(t * 512 + k) * 6 + e]);
    }
    WgT[(size_t)col * 512 + k] = v;
  }
}

// ================= 256x256 pipelined MFMA GEMM (triple-buffer, counted vmcnt) ======
// 512 threads = 8 waves (2M x 4N), wave tile 128x64 (8x4 frags of 16x16), BK=32.
// LDS: 3 buffers x (A 256x32 + B 256x32) u16 = 96 KB. K = 512 fixed (16 K-tiles).
// In-loop: stage kt+2 into spare buffer, compute kt, wait vmcnt(4) (kt+1 landed),
// one raw s_barrier per K-step. Chunk-XOR swizzle (2-way max -> free).
// TOWER: epilogue = relu(acc+bias) . tw2 -> shfl-reduce -> atomicAdd logits.
template <int RELU, int TOWER>
__global__ __launch_bounds__(512, 2) void gemm256(
    const u16* __restrict__ A, int lda, size_t zA,
    const u16* __restrict__ BT, size_t zB,
    const float* __restrict__ bias, int zBias,
    u16* __restrict__ C, int ldc, size_t zC,
    int nby,
    const float* __restrict__ tw2, float* __restrict__ logits) {
  int z = blockIdx.z;
  A += (size_t)z * zA;
  BT += (size_t)z * zB;
  bias += (size_t)z * zBias;
  C += (size_t)z * zC;

  // bijective XCD-chunk swizzle (gridDim.x % 8 == 0)
  int nwg = gridDim.x;
  int cpx = nwg >> 3;
  int bid = blockIdx.x;
  int swz = (bid & 7) * cpx + (bid >> 3);
  int bx = swz / nby, by = swz % nby;
  int brow = bx * 256, bcol = by * 256;

  __shared__ u16 SB[3][16384];  // [buf]: A u16 0..8191, B u16 8192..16383

  int tid = threadIdx.x, lane = tid & 63, w = tid >> 6;
  int wm = w >> 2, wn = w & 3;
  int l = lane & 15, q = lane >> 4;

  // staging: thread covers (row = tid>>2, chunk = tid&3) for rows 0..127, +128 on round 1
  int srow = tid >> 2;
  int sc = tid & 3;
  int srcc = sc ^ ((srow >> 1) & 3);   // same value for row+128
  const u16* AgR0 = A + (size_t)(brow + srow) * lda + srcc * 8;
  const u16* AgR1 = AgR0 + (size_t)128 * lda;
  const u16* BgR0 = BT + (size_t)(bcol + srow) * KDIM + srcc * 8;
  const u16* BgR1 = BgR0 + 128 * KDIM;
  int lo = w * 512;  // wave-uniform LDS offset (u16) within each 128-row half

#define STAGE256(buf, kt)                              \
  do {                                                 \
    int _ko = (kt) * 32;                               \
    gload16(AgR0 + _ko, (buf) + lo);                   \
    gload16(AgR1 + _ko, (buf) + 4096 + lo);            \
    gload16(BgR0 + _ko, (buf) + 8192 + lo);            \
    gload16(BgR1 + _ko, (buf) + 12288 + lo);           \
  } while (0)

  f32x4 zero; zero[0] = 0.f; zero[1] = 0.f; zero[2] = 0.f; zero[3] = 0.f;
  f32x4 acc[8][4];
#pragma unroll
  for (int m = 0; m < 8; m++)
#pragma unroll
    for (int n = 0; n < 4; n++) acc[m][n] = zero;

  int rca = q ^ ((l >> 1) & 3);  // swizzled read chunk (uniform across frags)
  int arow = wm * 128 + l;       // + m*16
  int bro = wn * 64 + l;         // + n*16

  STAGE256(SB[0], 0);
  STAGE256(SB[1], 1);
  asm volatile("s_waitcnt vmcnt(4)" ::: "memory");
  __builtin_amdgcn_s_barrier();

  u16 *bc = SB[0], *bn = SB[1], *bq = SB[2];
#pragma unroll
  for (int kt = 0; kt < 16; ++kt) {
    if (kt < 14) STAGE256(bq, kt + 2);
    bf16x8 af[8], bfv[4];
#pragma unroll
    for (int m = 0; m < 8; m++)
      af[m] = *(const bf16x8*)&bc[(arow + m * 16) * 32 + rca * 8];
#pragma unroll
    for (int n = 0; n < 4; n++)
      bfv[n] = *(const bf16x8*)&bc[8192 + (bro + n * 16) * 32 + rca * 8];
    __builtin_amdgcn_s_setprio(1);
#pragma unroll
    for (int m = 0; m < 8; m++)
#pragma unroll
      for (int n = 0; n < 4; n++)
        acc[m][n] = __builtin_amdgcn_mfma_f32_16x16x32_bf16(af[m], bfv[n], acc[m][n], 0, 0, 0);
    __builtin_amdgcn_s_setprio(0);
    asm volatile("s_waitcnt lgkmcnt(0)" ::: "memory");  // reads retired before re-stage
    if (kt < 14)
      asm volatile("s_waitcnt vmcnt(4)" ::: "memory");  // kt+1's 4 loads landed
    else
      asm volatile("s_waitcnt vmcnt(0)" ::: "memory");  // tail drain
    __builtin_amdgcn_s_barrier();
    u16* t_ = bc; bc = bn; bn = bq; bq = t_;
  }
#undef STAGE256

  int row0 = brow + wm * 128 + q * 4;
  int col0 = bcol + wn * 64 + l;
  if (!TOWER) {
#pragma unroll
    for (int n = 0; n < 4; n++) {
      int col = col0 + n * 16;
      float bv = bias[col];
#pragma unroll
      for (int m = 0; m < 8; m++) {
        int row = row0 + m * 16;
#pragma unroll
        for (int rr = 0; rr < 4; rr++) {
          float v = acc[m][n][rr] + bv;
          if (RELU) v = fmaxf(v, 0.f);
          C[(size_t)(row + rr) * ldc + col] = f2bf(v);
        }
      }
    }
  } else {
    int t = z;
    float bvs[4], tws[4];
#pragma unroll
    for (int n = 0; n < 4; n++) {
      int col = col0 + n * 16;
      bvs[n] = bias[col];
      tws[n] = tw2[t * 512 + col];
    }
#pragma unroll
    for (int m = 0; m < 8; m++) {
#pragma unroll
      for (int rr = 0; rr < 4; rr++) {
        float s = 0.f;
#pragma unroll
        for (int n = 0; n < 4; n++) {
          float v = acc[m][n][rr] + bvs[n];
          v = fmaxf(v, 0.f);
          s += v * tws[n];
        }
        s += __shfl_xor(s, 1, 64);
        s += __shfl_xor(s, 2, 64);
        s += __shfl_xor(s, 4, 64);
        s += __shfl_xor(s, 8, 64);
        if (l == 0) {
          int row = row0 + m * 16 + rr;
          int b = row / CDIM, c = row % CDIM;
          atomicAdd(&logits[(size_t)(b * TDIM + t) * CDIM + c], s);
        }
      }
    }
  }
}

// ---------------- bf16 MFMA GEMM (m97 structure, 128^2) for skinny fc1/fc2 ----
template <int RELU>
__global__ __launch_bounds__(256, 2) void gemm_bt(
    const u16* __restrict__ A, int lda,
    const u16* __restrict__ BT,
    const float* __restrict__ bias,
    u16* __restrict__ C, int ldc) {
  __shared__ u16 Al[128 * 32];
  __shared__ u16 Bl[128 * 32];
  int tid = threadIdx.x, lane = tid & 63, w = tid >> 6;
  int wr = w >> 1, wc = w & 1;
  int brow = blockIdx.x * 128, bcol = blockIdx.y * 128;

  int srow = tid >> 2;
  int schunk = tid & 3;
  int srcc = schunk ^ ((srow >> 1) & 3);
  const u16* Ag0 = A + (size_t)(brow + srow) * lda + srcc * 8;
  const u16* Ag1 = A + (size_t)(brow + srow + 64) * lda + srcc * 8;
  const u16* Bg0 = BT + (size_t)(bcol + srow) * KDIM + srcc * 8;
  const u16* Bg1 = BT + (size_t)(bcol + srow + 64) * KDIM + srcc * 8;
  u16* Ald0 = Al + w * 512;
  u16* Ald1 = Al + 2048 + w * 512;
  u16* Bld0 = Bl + w * 512;
  u16* Bld1 = Bl + 2048 + w * 512;

  f32x4 zero; zero[0] = 0.f; zero[1] = 0.f; zero[2] = 0.f; zero[3] = 0.f;
  f32x4 acc[4][4];
#pragma unroll
  for (int m = 0; m < 4; m++)
#pragma unroll
    for (int n = 0; n < 4; n++) acc[m][n] = zero;

  int l = lane & 15, q = lane >> 4;
  int rc = q ^ ((l >> 1) & 3);
  int rbase = wr * 64 + l;
  int cbase = wc * 64 + l;

  for (int kt = 0; kt < 16; ++kt) {
    int ko = kt * 32;
    gload16(Ag0 + ko, Ald0);
    gload16(Ag1 + ko, Ald1);
    gload16(Bg0 + ko, Bld0);
    gload16(Bg1 + ko, Bld1);
    __syncthreads();
    bf16x8 af[4], bfr[4];
#pragma unroll
    for (int m = 0; m < 4; m++) af[m] = *(const bf16x8*)&Al[(rbase + m * 16) * 32 + rc * 8];
#pragma unroll
    for (int n = 0; n < 4; n++) bfr[n] = *(const bf16x8*)&Bl[(cbase + n * 16) * 32 + rc * 8];
#pragma unroll
    for (int m = 0; m < 4; m++)
#pragma unroll
      for (int n = 0; n < 4; n++)
        acc[m][n] = __builtin_amdgcn_mfma_f32_16x16x32_bf16(af[m], bfr[n], acc[m][n], 0, 0, 0);
    __syncthreads();
  }

  int col0 = bcol + wc * 64 + l;
  int row0 = brow + wr * 64 + q * 4;
#pragma unroll
  for (int n = 0; n < 4; n++) {
    int col = col0 + n * 16;
    float bv = bias[col];
#pragma unroll
    for (int m = 0; m < 4; m++) {
      int row = row0 + m * 16;
#pragma unroll
      for (int r = 0; r < 4; r++) {
        float v = acc[m][n][r] + bv;
        if (RELU) v = fmaxf(v, 0.f);
        C[(size_t)(row + r) * ldc + col] = f2bf(v);
      }
    }
  }
}

// ---------------- gate: MFMA skinny GEMM [64 rows/block x 32] + top3 softmax ----
__global__ __launch_bounds__(256) void gate_kernel(const u16* __restrict__ h,
                                                   const u16* __restrict__ WgT,
                                                   float* __restrict__ gates) {
  __shared__ u16 Wl[16 * 32 * 32];
  __shared__ float Gl[4][16][33];
  int tid = threadIdx.x, lane = tid & 63, w = tid >> 6;
  int l = lane & 15, q = lane >> 4;

  for (int idx = tid; idx < 2048; idx += 256) {
    int kt = idx >> 7, col = (idx >> 2) & 31, c = idx & 3;
    int sc = c ^ ((col >> 1) & 3);
    *(u16x8*)&Wl[kt * 1024 + col * 32 + c * 8] =
        *(const u16x8*)&WgT[(size_t)col * 512 + kt * 32 + sc * 8];
  }
  __syncthreads();

  int r = blockIdx.x * 64 + w * 16 + l;
  int ch = q ^ ((l >> 1) & 3);

  f32x4 acc0, acc1;
  acc0[0] = acc0[1] = acc0[2] = acc0[3] = 0.f;
  acc1 = acc0;
#pragma unroll
  for (int kt = 0; kt < 16; ++kt) {
    bf16x8 av = *(const bf16x8*)&h[(size_t)r * 512 + kt * 32 + q * 8];
    bf16x8 b0 = *(const bf16x8*)&Wl[kt * 1024 + l * 32 + ch * 8];
    bf16x8 b1 = *(const bf16x8*)&Wl[kt * 1024 + (16 + l) * 32 + ch * 8];
    acc0 = __builtin_amdgcn_mfma_f32_16x16x32_bf16(av, b0, acc0, 0, 0, 0);
    acc1 = __builtin_amdgcn_mfma_f32_16x16x32_bf16(av, b1, acc1, 0, 0, 0);
  }

#pragma unroll
  for (int rr = 0; rr < 4; rr++) {
    Gl[w][q * 4 + rr][l] = acc0[rr];
    Gl[w][q * 4 + rr][16 + l] = acc1[rr];
  }
  __syncthreads();

  if (lane < 16) {
    int R = blockIdx.x * 64 + w * 16 + lane;
    int b = R / CDIM, c = R % CDIM;
    for (int t = 0; t < 3; t++) {
      float g[6];
#pragma unroll
      for (int e = 0; e < 6; e++) g[e] = Gl[w][lane][t * 6 + e];
      float out[6] = {0, 0, 0, 0, 0, 0};
      int idx[3]; float val[3];
      unsigned used = 0;
      for (int kk = 0; kk < 3; kk++) {
        int best = 0; float bv = -1e30f;
        for (int e = 0; e < 6; e++)
          if (!((used >> e) & 1) && g[e] > bv) { bv = g[e]; best = e; }
        used |= 1u << best; idx[kk] = best; val[kk] = bv;
      }
      float mx = val[0];
      float s = 0.f, ex[3];
      for (int kk = 0; kk < 3; kk++) { ex[kk] = expf(val[kk] - mx); s += ex[kk]; }
      for (int kk = 0; kk < 3; kk++) out[idx[kk]] = ex[kk] / s;
      float* gp = &gates[(size_t)((b * TDIM + t) * CDIM + c) * EDIM];
      for (int e = 0; e < 6; e++) gp[e] = out[e];
    }
  }
}

// ---------------- combine: y[t][r][:] = sum_e gates[b,t,c,e] * eo[r][e*512:+512] ----
__global__ __launch_bounds__(256) void combine_kernel(const u16* __restrict__ eo,
                                                      const float* __restrict__ gates,
                                                      u16* __restrict__ y) {
  int w = threadIdx.x >> 6, lane = threadIdx.x & 63;
  int r = blockIdx.x * 4 + w;
  if (r >= NROWS) return;
  int b = r / CDIM, c = r % CDIM;
  float g[3][6];
#pragma unroll
  for (int t = 0; t < 3; t++)
#pragma unroll
    for (int e = 0; e < 6; e++)
      g[t][e] = gates[(size_t)((b * TDIM + t) * CDIM + c) * EDIM + e];

  const u16x8* ep = (const u16x8*)&eo[(size_t)r * (EDIM * 512) + lane * 8];
  float yacc[3][8];
#pragma unroll
  for (int t = 0; t < 3; t++)
#pragma unroll
    for (int j = 0; j < 8; j++) yacc[t][j] = 0.f;
#pragma unroll
  for (int e = 0; e < 6; e++) {
    u16x8 ev = ep[e * 64];
    float evf[8];
#pragma unroll
    for (int j = 0; j < 8; j++) evf[j] = bf2f(ev[j]);
#pragma unroll
    for (int t = 0; t < 3; t++)
#pragma unroll
      for (int j = 0; j < 8; j++) yacc[t][j] += g[t][e] * evf[j];
  }
#pragma unroll
  for (int t = 0; t < 3; t++) {
    u16x8 ov;
#pragma unroll
    for (int j = 0; j < 8; j++) ov[j] = f2bf(yacc[t][j]);
    *(u16x8*)&y[((size_t)t * NROWS + r) * 512 + lane * 8] = ov;
  }
}

// ---------------- loss: one wave per b ----------------
__global__ __launch_bounds__(64) void loss_kernel(const float* __restrict__ scores,
                                                  const float* __restrict__ logits,
                                                  const float* __restrict__ gates,
                                                  const float* __restrict__ tb2,
                                                  float* __restrict__ out) {
  int b = blockIdx.x;
  int lane = threadIdx.x;
  float bce_sum = 0.f;
  float aux = 0.f;
  for (int t = 0; t < 3; t++) {
    float sc = (lane < CDIM) ? scores[(size_t)(b * TDIM + t) * CDIM + lane] : -1e30f;
    float mx = sc;
    for (int off = 32; off; off >>= 1) mx = fmaxf(mx, __shfl_xor(mx, off, 64));
    float lab = (lane < CDIM && sc == mx) ? 1.f : 0.f;
    float lg = (lane < CDIM) ? (logits[(size_t)(b * TDIM + t) * CDIM + lane] + tb2[t]) : 0.f;
    float bce = (lane < CDIM) ? (fmaxf(lg, 0.f) - lg * lab + log1pf(expf(-fabsf(lg)))) : 0.f;
    for (int off = 32; off; off >>= 1) bce += __shfl_xor(bce, off, 64);
    bce_sum += bce / (float)CDIM;

    float impv[6];
    float meansum = 0.f;
#pragma unroll
    for (int e = 0; e < 6; e++) {
      float gsum = (lane < CDIM) ? gates[(size_t)((b * TDIM + t) * CDIM + lane) * EDIM + e] : 0.f;
      for (int off = 32; off; off >>= 1) gsum += __shfl_xor(gsum, off, 64);
      impv[e] = gsum;
      meansum += gsum;
    }
    float mean = meansum / 6.f;
    float var = 0.f;
#pragma unroll
    for (int e = 0; e < 6; e++) { float d = impv[e] - mean; var += d * d; }
    var /= 6.f;
    aux += var / (mean * mean + 1e-10f);
  }
  float res = bce_sum / 3.f + 0.01f * aux;
  if (lane == 0) atomicAdd(out, res / (float)BDIM);
}

// ---------------- host ----------------
extern "C" void kernel_launch(void* const* d_in, const int* in_sizes, int n_in,
                              void* d_out, int out_size, void* d_ws, size_t ws_size,
                              hipStream_t stream) {
  const float* X = (const float*)d_in[0];
  const float* scores = (const float*)d_in[1];
  const float* fc1_w = (const float*)d_in[2];
  const float* fc1_b = (const float*)d_in[3];
  const float* fc2_w = (const float*)d_in[4];
  const float* fc2_b = (const float*)d_in[5];
  const float* w_gate = (const float*)d_in[6];
  const float* ew1 = (const float*)d_in[7];
  const float* eb1 = (const float*)d_in[8];
  const float* ew2 = (const float*)d_in[9];
  const float* eb2 = (const float*)d_in[10];
  const float* tw1 = (const float*)d_in[11];
  const float* tb1 = (const float*)d_in[12];
  const float* tw2 = (const float*)d_in[13];
  const float* tb2 = (const float*)d_in[14];
  float* out = (float*)d_out;

  // workspace layout (u16 elements); eh_all overlaps {Xb, A1, y} (lifetimes disjoint)
  u16* WT = (u16*)d_ws;                          // 17*262144
  u16* WgT = WT + (size_t)17 * 262144;           // 32*512
  u16* ehall = WgT + (size_t)32 * 512;           // 15360*3072
  u16* Xb = ehall;                               // dead after fc1
  u16* A1 = ehall + (size_t)NROWS * 512;         // dead after fc2
  u16* y = ehall;                                // written after ehall dead
  u16* h = ehall + (size_t)NROWS * 3072;         // 15360*512
  u16* eo = h + (size_t)NROWS * 512;             // 15360*3072
  float* gates = (float*)(eo + (size_t)NROWS * 3072);
  float* logits = gates + (size_t)BDIM * TDIM * CDIM * EDIM;

  hipMemsetAsync(d_out, 0, sizeof(float) * out_size, stream);
  hipMemsetAsync(logits, 0, sizeof(float) * BDIM * TDIM * CDIM, stream);

  cvt_bf16_kernel<<<3840, 256, 0, stream>>>(X, Xb, NROWS * 512);
  transpose_w_kernel<<<dim3(64, 17), 256, 0, stream>>>(fc1_w, fc2_w, ew1, ew2, tw1, WT);
  gate_w_prep<<<32, 256, 0, stream>>>(w_gate, WgT);

  // shared bottom (128^2, N=512 -> 480 blocks)
  gemm_bt<1><<<dim3(120, 4), 256, 0, stream>>>(Xb, 512, WT + (size_t)0 * 262144, fc1_b, A1, 512);
  gemm_bt<0><<<dim3(120, 4), 256, 0, stream>>>(A1, 512, WT + (size_t)1 * 262144, fc2_b, h, 512);

  // gating
  gate_kernel<<<240, 256, 0, stream>>>(h, WgT, gates);

  // experts W1: merged N=3072, 256^2 pipelined (60x12 = 720 blocks)
  gemm256<1, 0><<<dim3(720, 1, 1), 512, 0, stream>>>(
      h, 512, 0, WT + (size_t)2 * 262144, 0, eb1, 0, ehall, 3072, 0, 12, nullptr, nullptr);

  // experts W2: z-batched over 6 experts (60x2 x 6 = 720 blocks)
  gemm256<0, 0><<<dim3(120, 1, 6), 512, 0, stream>>>(
      ehall, 3072, 512, WT + (size_t)8 * 262144, 262144, eb2, 512, eo, 3072, 512, 2,
      nullptr, nullptr);

  // gated combine
  combine_kernel<<<3840, 256, 0, stream>>>(eo, gates, y);

  // towers: 256^2 + fused tw2-dot epilogue -> logits (atomic), z = task
  gemm256<0, 1><<<dim3(120, 1, 3), 512, 0, stream>>>(
      y, 512, (size_t)NROWS * 512, WT + (size_t)14 * 262144, 262144, tb1, 512,
      nullptr, 0, 0, 2, tw2, logits);

  // loss
  loss_kernel<<<BDIM, 64, 0, stream>>>(scores, logits, gates, tb2, out);
}